// Round 6
// baseline (352.244 us; speedup 1.0000x reference)
//
#include <hip/hip_runtime.h>
#include <hip/hip_bf16.h>
#include <math.h>

// Problem constants (reference: T=1024, B=4, D=1024, E=8, K=2, H=2048, O=1024)
#define T_DIM 1024
#define B_DIM 4
#define D_DIM 1024
#define N_TOK (T_DIM * B_DIM)   // 4096 tokens
#define E_NUM 8
#define K_TOP 2
#define H_DIM 2048
#define O_DIM 1024
#define MAX_YSLOTS 72           // sum ceil(cnt_e/128) <= 8192/128 + 8 = 72

typedef __attribute__((ext_vector_type(8))) short bf16x8;
typedef __attribute__((ext_vector_type(4))) float f32x4;

__device__ __forceinline__ float gelu_exact(float x) {
    return 0.5f * x * (1.0f + erff(x * 0.7071067811865476f));
}

__device__ __forceinline__ unsigned short f2bf(float f) {
    union { __hip_bfloat16 h; unsigned short u; } c;
    c.h = __float2bfloat16(f);
    return c.u;
}

__device__ __forceinline__ void gload_lds16(const void* g, void* l) {
    __builtin_amdgcn_global_load_lds(
        (const __attribute__((address_space(1))) void*)g,
        (__attribute__((address_space(3))) void*)l,
        16, 0, 0);
}

// ---------------------------------------------------------------------------
// Kernel 1: LayerNorm + router + top-2.  One WAVE per token, NO atomics.
// ---------------------------------------------------------------------------
__global__ __launch_bounds__(256) void ln_router_kernel(
    const float* __restrict__ x,        // [N, D]
    const float* __restrict__ seq_mask, // [N]
    const float* __restrict__ ln_scale, // [D]
    const float* __restrict__ ln_bias,  // [D]
    const float* __restrict__ router_w, // [E, D]
    unsigned short* __restrict__ xn,    // ws: [N, D] bf16
    float* __restrict__ gate_out,       // out: [N, E]
    unsigned int* __restrict__ tok_e,   // ws: [N]  e0 | e1<<8
    float2* __restrict__ tok_p)         // ws: [N]  (p0*msk, p1*msk)
{
    const int wv = threadIdx.x >> 6;
    const int ln = threadIdx.x & 63;
    const int n = blockIdx.x * 4 + wv;

    const float* xr = x + (size_t)n * D_DIM;

    float v[4][4];
    float sum = 0.f, sumsq = 0.f;
#pragma unroll
    for (int p = 0; p < 4; ++p) {
        float4 t = *(const float4*)&xr[ln * 4 + p * 256];
        v[p][0] = t.x; v[p][1] = t.y; v[p][2] = t.z; v[p][3] = t.w;
#pragma unroll
        for (int c = 0; c < 4; ++c) { sum += v[p][c]; sumsq += v[p][c] * v[p][c]; }
    }
#pragma unroll
    for (int m = 1; m < 64; m <<= 1) {
        sum   += __shfl_xor(sum, m, 64);
        sumsq += __shfl_xor(sumsq, m, 64);
    }
    const float mu = sum * (1.0f / D_DIM);
    const float var = sumsq * (1.0f / D_DIM) - mu * mu;
    const float rstd = rsqrtf(var + 1e-5f);

    float xv[4][4];
#pragma unroll
    for (int p = 0; p < 4; ++p) {
        int col = ln * 4 + p * 256;
        float4 sc = *(const float4*)&ln_scale[col];
        float4 bi = *(const float4*)&ln_bias[col];
        const float* scp = (const float*)&sc;
        const float* bip = (const float*)&bi;
        ushort4 o;
        unsigned short* op = (unsigned short*)&o;
#pragma unroll
        for (int c = 0; c < 4; ++c) {
            float t = (v[p][c] - mu) * rstd * scp[c] + bip[c];
            xv[p][c] = t;
            op[c] = f2bf(t);
        }
        *(ushort4*)&xn[(size_t)n * D_DIM + col] = o;
    }

    float dot[E_NUM];
#pragma unroll
    for (int e = 0; e < E_NUM; ++e) {
        const float* rw = router_w + (size_t)e * D_DIM;
        float a = 0.f;
#pragma unroll
        for (int p = 0; p < 4; ++p) {
            float4 t = *(const float4*)&rw[ln * 4 + p * 256];
            const float* tp = (const float*)&t;
#pragma unroll
            for (int c = 0; c < 4; ++c) a += xv[p][c] * tp[c];
        }
        dot[e] = a;
    }
#pragma unroll
    for (int e = 0; e < E_NUM; ++e)
#pragma unroll
        for (int m = 1; m < 64; m <<= 1) dot[e] += __shfl_xor(dot[e], m, 64);

    if (ln == 0) {
        float4 g0 = make_float4(dot[0], dot[1], dot[2], dot[3]);
        float4 g1 = make_float4(dot[4], dot[5], dot[6], dot[7]);
        *(float4*)&gate_out[(size_t)n * E_NUM] = g0;
        *(float4*)&gate_out[(size_t)n * E_NUM + 4] = g1;

        int i0 = 0; float l0 = dot[0];
        for (int e = 1; e < E_NUM; ++e)
            if (dot[e] > l0) { l0 = dot[e]; i0 = e; }
        int i1 = -1; float l1 = -INFINITY;
        for (int e = 0; e < E_NUM; ++e) {
            if (e == i0) continue;
            if (dot[e] > l1) { l1 = dot[e]; i1 = e; }
        }
        float z = __expf(l1 - l0);
        float p0 = 1.0f / (1.0f + z);
        float p1 = z / (1.0f + z);
        float msk = seq_mask[n];

        tok_e[n] = (unsigned)i0 | ((unsigned)i1 << 8);
        tok_p[n] = make_float2(p0 * msk, p1 * msk);
    }
}

// ---------------------------------------------------------------------------
// Build per-expert token lists via ballot prefix-scan. grid = 8.
// ---------------------------------------------------------------------------
__global__ __launch_bounds__(256) void build_lists(
    const unsigned int* __restrict__ tok_e,
    const float2* __restrict__ tok_p,
    int* __restrict__ counts,   // [E]
    int* __restrict__ perm,     // [E, N]
    int* __restrict__ hrow,     // [E, N]
    float* __restrict__ probs)  // [E, N]
{
    const int e = blockIdx.x;
    const int tid = threadIdx.x;
    const int wv = tid >> 6, ln = tid & 63;
    __shared__ int s_base;
    __shared__ int wave_tot[4];
    if (tid == 0) s_base = 0;
    __syncthreads();

    for (int t0 = 0; t0 < N_TOK; t0 += 256) {
        int t = t0 + tid;
        unsigned pk = tok_e[t];
        int m1 = (((pk >> 8) & 0xffu) == (unsigned)e);
        int m = (((pk & 0xffu) == (unsigned)e) | m1);
        unsigned long long bal = __ballot(m);
        int pre = __popcll(bal & ((1ull << ln) - 1ull));
        if (ln == 0) wave_tot[wv] = __popcll(bal);
        __syncthreads();
        int base = s_base;
        int wbase = 0;
#pragma unroll
        for (int w = 0; w < 4; ++w) if (w < wv) wbase += wave_tot[w];
        int total = wave_tot[0] + wave_tot[1] + wave_tot[2] + wave_tot[3];
        __syncthreads();
        if (m) {
            int pos = base + wbase + pre;
            perm[e * N_TOK + pos] = t;
            hrow[e * N_TOK + pos] = t * 2 + m1;
            float2 p = tok_p[t];
            probs[e * N_TOK + pos] = m1 ? p.y : p.x;
        }
        if (tid == 0) s_base = base + total;
        __syncthreads();
    }
    if (tid == 0) counts[e] = s_base;
}

// ---------------------------------------------------------------------------
// fp32 [E][K][N] -> bf16 [E][N][K] transpose+convert. 64x64 tiles.
// ---------------------------------------------------------------------------
__global__ __launch_bounds__(256) void transpose_convert(
    const float* __restrict__ src, unsigned short* __restrict__ dst,
    int K, int N)
{
    __shared__ float ts[64][65];
    const int e = blockIdx.z;
    const int n0 = blockIdx.x * 64;
    const int k0 = blockIdx.y * 64;
    const float* S = src + (size_t)e * K * N;
    unsigned short* D = dst + (size_t)e * N * K;
    const int tid = threadIdx.x;
    const int r = tid >> 4, c4 = (tid & 15) * 4;

#pragma unroll
    for (int j = 0; j < 4; ++j) {
        float4 v = *(const float4*)&S[(size_t)(k0 + r + 16 * j) * N + n0 + c4];
        ts[r + 16 * j][c4 + 0] = v.x;
        ts[r + 16 * j][c4 + 1] = v.y;
        ts[r + 16 * j][c4 + 2] = v.z;
        ts[r + 16 * j][c4 + 3] = v.w;
    }
    __syncthreads();
#pragma unroll
    for (int j = 0; j < 4; ++j) {
        int nn = r + 16 * j;
        ushort4 o;
        o.x = f2bf(ts[c4 + 0][nn]);
        o.y = f2bf(ts[c4 + 1][nn]);
        o.z = f2bf(ts[c4 + 2][nn]);
        o.w = f2bf(ts[c4 + 3][nn]);
        *(ushort4*)&D[(size_t)(n0 + nn) * K + k0 + c4] = o;
    }
}

// ---------------------------------------------------------------------------
// Map a dense y-slot to (expert, m0) from counts. Wave-uniform scalar math.
// ---------------------------------------------------------------------------
__device__ __forceinline__ int slot_to_tile(const int* counts, int yslot, int* m0) {
    int e = -1, acc = 0, m = 0;
#pragma unroll
    for (int ee = 0; ee < E_NUM; ++ee) {
        int t = (counts[ee] + 127) >> 7;
        if (e < 0 && yslot < acc + t) { e = ee; m = (yslot - acc) << 7; }
        acc += t;
    }
    *m0 = m;
    return e;
}

// ---------------------------------------------------------------------------
// MFMA expert GEMM stage 1: h = gelu( gather(xn) @ w1t^T + b1 )
// 128x128 tile, BK=32, double-buffered LDS, 256 thr, wave-tile 64x64.
// grid = (H/128, MAX_YSLOTS)
// ---------------------------------------------------------------------------
#define TBUF (128 * 64)   // one LDS buffer: 128 rows x 32 k x bf16 = 8 KB

__global__ __launch_bounds__(256) void expert_gemm1(
    const unsigned short* __restrict__ xn,   // [N_TOK][D] bf16
    const unsigned short* __restrict__ wt1,  // [E][H][D] bf16 (transposed)
    const float* __restrict__ b1,            // [E][H]
    const int* __restrict__ counts,
    const int* __restrict__ perm,
    const int* __restrict__ hrow,
    unsigned short* __restrict__ hbuf)       // [N_TOK*2][H] bf16
{
    int m0;
    const int e = slot_to_tile(counts, blockIdx.y, &m0);
    if (e < 0) return;
    const int cnt = counts[e];
    const int n0 = blockIdx.x * 128;
    const int tid = threadIdx.x;
    const int wv = tid >> 6, ln = tid & 63;
    const int ml = ln & 15, q = ln >> 4;
    const int wm = (wv & 1) * 64, wn = (wv >> 1) * 64;

    __shared__ __align__(16) unsigned char As[2 * TBUF];
    __shared__ __align__(16) unsigned char Bs[2 * TBUF];
    __shared__ int s_tok[128];
    __shared__ int s_hr[128];

    if (tid < 128) {
        int m = m0 + tid;
        int ok = (m < cnt);
        s_tok[tid] = ok ? perm[e * N_TOK + m] : 0;
        s_hr[tid]  = ok ? hrow[e * N_TOK + m] : 0;
    }
    __syncthreads();

    const unsigned short* wte = wt1 + (size_t)e * H_DIM * D_DIM;
    const unsigned short* agp[2]; int alds[2];
    const unsigned short* bgp[2]; int blds[2];
#pragma unroll
    for (int j = 0; j < 2; ++j) {
        int slot = j * 256 + tid;
        int r = slot >> 2, ss = slot & 3;
        int sg = ss ^ ((r >> 1) & 3);           // XOR swizzle (64B row stride)
        agp[j] = xn + (size_t)s_tok[r] * D_DIM + sg * 8;
        alds[j] = slot * 16;
        bgp[j] = wte + (size_t)(n0 + r) * D_DIM + sg * 8;
        blds[j] = slot * 16;
    }

    // prefetch tile 0 into buffer 0
#pragma unroll
    for (int j = 0; j < 2; ++j) {
        gload_lds16(agp[j], As + alds[j]);
        gload_lds16(bgp[j], Bs + blds[j]);
    }

    f32x4 acc[4][4] = {};
    const int rslot = (q ^ ((ml >> 1) & 3)) * 16;
    int cur = 0;

    for (int k0 = 0; k0 < D_DIM; k0 += 32) {
        __syncthreads();   // implicit vmcnt(0): tile k0 present in buf cur;
                           // also all prior reads of buf cur^1 complete
        if (k0 + 32 < D_DIM) {
            const int nb = (cur ^ 1) * TBUF;
#pragma unroll
            for (int j = 0; j < 2; ++j) {
                gload_lds16(agp[j] + k0 + 32, As + nb + alds[j]);
                gload_lds16(bgp[j] + k0 + 32, Bs + nb + blds[j]);
            }
        }
        const unsigned char* Ab = As + cur * TBUF;
        const unsigned char* Bb = Bs + cur * TBUF;
        bf16x8 af[4], bfr[4];
#pragma unroll
        for (int i = 0; i < 4; ++i)
            af[i] = *(const bf16x8*)(Ab + (wm + i * 16 + ml) * 64 + rslot);
#pragma unroll
        for (int j = 0; j < 4; ++j)
            bfr[j] = *(const bf16x8*)(Bb + (wn + j * 16 + ml) * 64 + rslot);
#pragma unroll
        for (int i = 0; i < 4; ++i)
#pragma unroll
            for (int j = 0; j < 4; ++j)
                acc[i][j] = __builtin_amdgcn_mfma_f32_16x16x32_bf16(
                    af[i], bfr[j], acc[i][j], 0, 0, 0);
        cur ^= 1;
    }

    float bias[4];
#pragma unroll
    for (int j = 0; j < 4; ++j)
        bias[j] = b1[(size_t)e * H_DIM + n0 + wn + j * 16 + ml];

#pragma unroll
    for (int i = 0; i < 4; ++i) {
#pragma unroll
        for (int r = 0; r < 4; ++r) {
            int rl = wm + i * 16 + q * 4 + r;
            if (m0 + rl < cnt) {
                int hr = s_hr[rl];
                unsigned short* dst = hbuf + (size_t)hr * H_DIM + n0 + wn + ml;
#pragma unroll
                for (int j = 0; j < 4; ++j)
                    dst[j * 16] = f2bf(gelu_exact(acc[i][j][r] + bias[j]));
            }
        }
    }
}

// ---------------------------------------------------------------------------
// MFMA expert GEMM stage 2: ybuf[hr] = prob * gelu( h @ w2t^T + b2 )
// 128x128 tile, BK=32, double-buffered LDS, 512 thr, wave-tile 32x64.
// grid = (O/128, MAX_YSLOTS)
// ---------------------------------------------------------------------------
__global__ __launch_bounds__(512) void expert_gemm2(
    const unsigned short* __restrict__ hbuf, // [N_TOK*2][H] bf16
    const unsigned short* __restrict__ wt2,  // [E][O][H] bf16 (transposed)
    const float* __restrict__ b2,            // [E][O]
    const int* __restrict__ counts,
    const int* __restrict__ perm,
    const int* __restrict__ hrow,
    const float* __restrict__ probs,
    float* __restrict__ ybuf)                // [N_TOK*2][O] fp32
{
    int m0;
    const int e = slot_to_tile(counts, blockIdx.y, &m0);
    if (e < 0) return;
    const int cnt = counts[e];
    const int n0 = blockIdx.x * 128;
    const int tid = threadIdx.x;
    const int wv = tid >> 6, ln = tid & 63;
    const int ml = ln & 15, q = ln >> 4;
    const int wm = (wv & 3) * 32;       // 4 waves in m: rows wm..wm+31
    const int wn = (wv >> 2) * 64;      // 2 waves in n: cols wn..wn+63

    __shared__ __align__(16) unsigned char As[2 * TBUF];
    __shared__ __align__(16) unsigned char Bs[2 * TBUF];
    __shared__ int s_hr[128];
    __shared__ float s_p[128];

    if (tid < 128) {
        int m = m0 + tid;
        int ok = (m < cnt);
        s_hr[tid] = ok ? hrow[e * N_TOK + m] : 0;
        s_p[tid]  = ok ? probs[e * N_TOK + m] : 0.f;
    }
    __syncthreads();

    const unsigned short* wte = wt2 + (size_t)e * O_DIM * H_DIM;
    // 512 threads: 1 A-chunk + 1 B-chunk each
    const int r_ = tid >> 2, ss = tid & 3;
    const int sg = ss ^ ((r_ >> 1) & 3);
    const unsigned short* agp = hbuf + (size_t)s_hr[r_] * H_DIM + sg * 8;
    const int alds = tid * 16;
    const unsigned short* bgp = wte + (size_t)(n0 + r_) * H_DIM + sg * 8;
    const int blds = tid * 16;

    // prefetch tile 0 into buffer 0
    gload_lds16(agp, As + alds);
    gload_lds16(bgp, Bs + blds);

    f32x4 acc[2][4] = {};
    const int rslot = (q ^ ((ml >> 1) & 3)) * 16;
    int cur = 0;

    for (int k0 = 0; k0 < H_DIM; k0 += 32) {
        __syncthreads();
        if (k0 + 32 < H_DIM) {
            const int nb = (cur ^ 1) * TBUF;
            gload_lds16(agp + k0 + 32, As + nb + alds);
            gload_lds16(bgp + k0 + 32, Bs + nb + blds);
        }
        const unsigned char* Ab = As + cur * TBUF;
        const unsigned char* Bb = Bs + cur * TBUF;
        bf16x8 af[2], bfr[4];
#pragma unroll
        for (int i = 0; i < 2; ++i)
            af[i] = *(const bf16x8*)(Ab + (wm + i * 16 + ml) * 64 + rslot);
#pragma unroll
        for (int j = 0; j < 4; ++j)
            bfr[j] = *(const bf16x8*)(Bb + (wn + j * 16 + ml) * 64 + rslot);
#pragma unroll
        for (int i = 0; i < 2; ++i)
#pragma unroll
            for (int j = 0; j < 4; ++j)
                acc[i][j] = __builtin_amdgcn_mfma_f32_16x16x32_bf16(
                    af[i], bfr[j], acc[i][j], 0, 0, 0);
        cur ^= 1;
    }

    float bias[4];
#pragma unroll
    for (int j = 0; j < 4; ++j)
        bias[j] = b2[(size_t)e * O_DIM + n0 + wn + j * 16 + ml];

#pragma unroll
    for (int i = 0; i < 2; ++i) {
#pragma unroll
        for (int r = 0; r < 4; ++r) {
            int rl = wm + i * 16 + q * 4 + r;
            if (m0 + rl < cnt) {
                int hr = s_hr[rl];
                float p = s_p[rl];
                float* dst = ybuf + (size_t)hr * O_DIM + n0 + wn + ml;
#pragma unroll
                for (int j = 0; j < 4; ++j)
                    dst[j * 16] = gelu_exact(acc[i][j][r] + bias[j]) * p;
            }
        }
    }
}

// ---------------------------------------------------------------------------
// combine: out[t] = ybuf[2t] + ybuf[2t+1]
// ---------------------------------------------------------------------------
__global__ __launch_bounds__(256) void combine_kernel(
    const float* __restrict__ ybuf, float* __restrict__ out)
{
    const size_t i = ((size_t)blockIdx.x * 256 + threadIdx.x) * 4;
    const size_t t = i / O_DIM;
    const size_t o = i % O_DIM;
    float4 a = *(const float4*)&ybuf[(t * 2) * O_DIM + o];
    float4 b = *(const float4*)&ybuf[(t * 2 + 1) * O_DIM + o];
    float4 r = make_float4(a.x + b.x, a.y + b.y, a.z + b.z, a.w + b.w);
    *(float4*)&out[i] = r;
}

// ---------------------------------------------------------------------------
extern "C" void kernel_launch(void* const* d_in, const int* in_sizes, int n_in,
                              void* d_out, int out_size, void* d_ws, size_t ws_size,
                              hipStream_t stream) {
    const float* x        = (const float*)d_in[0];
    const float* seq_mask = (const float*)d_in[1];
    const float* ln_scale = (const float*)d_in[2];
    const float* ln_bias  = (const float*)d_in[3];
    const float* router_w = (const float*)d_in[4];
    const float* w1       = (const float*)d_in[5];
    const float* b1       = (const float*)d_in[6];
    const float* w2       = (const float*)d_in[7];
    const float* b2       = (const float*)d_in[8];

    float* out      = (float*)d_out;               // [N, O]
    float* gate_out = out + (size_t)N_TOK * O_DIM; // [N, E]

    // workspace layout (~110 MB)
    char* ws = (char*)d_ws;
    unsigned short* xn = (unsigned short*)ws;              // N*D bf16   (8.4 MB)
    ws += (size_t)N_TOK * D_DIM * 2;
    unsigned short* wt = (unsigned short*)ws;              // E*H*D bf16 (33.6 MB, shared w1t/w2t)
    ws += (size_t)E_NUM * H_DIM * D_DIM * 2;
    unsigned short* hbuf = (unsigned short*)ws;            // 8192*H bf16 (33.6 MB)
    ws += (size_t)N_TOK * K_TOP * H_DIM * 2;
    float* ybuf = (float*)ws;                              // 8192*O fp32 (33.6 MB)
    ws += (size_t)N_TOK * K_TOP * O_DIM * 4;
    unsigned int* tok_e = (unsigned int*)ws; ws += (size_t)N_TOK * 4;
    float2* tok_p = (float2*)ws; ws += (size_t)N_TOK * 8;
    int* counts = (int*)ws; ws += 256;
    int* perm = (int*)ws;  ws += (size_t)E_NUM * N_TOK * 4;
    int* hrow = (int*)ws;  ws += (size_t)E_NUM * N_TOK * 4;
    float* probs = (float*)ws;

    ln_router_kernel<<<N_TOK / 4, 256, 0, stream>>>(
        x, seq_mask, ln_scale, ln_bias, router_w,
        xn, gate_out, tok_e, tok_p);

    build_lists<<<E_NUM, 256, 0, stream>>>(
        tok_e, tok_p, counts, perm, hrow, probs);

    // w1 [E][D][H] -> wt [E][H][D]
    transpose_convert<<<dim3(H_DIM / 64, D_DIM / 64, E_NUM), 256, 0, stream>>>(
        w1, wt, D_DIM, H_DIM);

    expert_gemm1<<<dim3(H_DIM / 128, MAX_YSLOTS), 256, 0, stream>>>(
        xn, wt, b1, counts, perm, hrow, hbuf);

    // w2 [E][H][O] -> wt [E][O][H]
    transpose_convert<<<dim3(O_DIM / 64, H_DIM / 64, E_NUM), 256, 0, stream>>>(
        w2, wt, H_DIM, O_DIM);

    expert_gemm2<<<dim3(O_DIM / 128, MAX_YSLOTS), 512, 0, stream>>>(
        hbuf, wt, b2, counts, perm, hrow, probs, ybuf);

    combine_kernel<<<(N_TOK * O_DIM / 4) / 256, 256, 0, stream>>>(ybuf, out);
}

// Round 7
// 342.823 us; speedup vs baseline: 1.0275x; 1.0275x over previous
//
#include <hip/hip_runtime.h>
#include <hip/hip_bf16.h>
#include <math.h>

// Problem constants (reference: T=1024, B=4, D=1024, E=8, K=2, H=2048, O=1024)
#define T_DIM 1024
#define B_DIM 4
#define D_DIM 1024
#define N_TOK (T_DIM * B_DIM)   // 4096 tokens
#define E_NUM 8
#define K_TOP 2
#define H_DIM 2048
#define O_DIM 1024
#define MAX_YSLOTS 72           // sum ceil(cnt_e/128) <= 8192/128 + 8 = 72

typedef __attribute__((ext_vector_type(8))) short bf16x8;
typedef __attribute__((ext_vector_type(4))) float f32x4;

__device__ __forceinline__ float gelu_exact(float x) {
    return 0.5f * x * (1.0f + erff(x * 0.7071067811865476f));
}

__device__ __forceinline__ unsigned short f2bf(float f) {
    union { __hip_bfloat16 h; unsigned short u; } c;
    c.h = __float2bfloat16(f);
    return c.u;
}

__device__ __forceinline__ void gload_lds16(const void* g, void* l) {
    __builtin_amdgcn_global_load_lds(
        (const __attribute__((address_space(1))) void*)g,
        (__attribute__((address_space(3))) void*)l,
        16, 0, 0);
}

// ---------------------------------------------------------------------------
// Kernel 1: LayerNorm + router + top-2.  One WAVE per token, NO atomics.
// ---------------------------------------------------------------------------
__global__ __launch_bounds__(256) void ln_router_kernel(
    const float* __restrict__ x,        // [N, D]
    const float* __restrict__ seq_mask, // [N]
    const float* __restrict__ ln_scale, // [D]
    const float* __restrict__ ln_bias,  // [D]
    const float* __restrict__ router_w, // [E, D]
    unsigned short* __restrict__ xn,    // ws: [N, D] bf16
    float* __restrict__ gate_out,       // out: [N, E]
    unsigned int* __restrict__ tok_e,   // ws: [N]  e0 | e1<<8
    float2* __restrict__ tok_p)         // ws: [N]  (p0*msk, p1*msk)
{
    const int wv = threadIdx.x >> 6;
    const int ln = threadIdx.x & 63;
    const int n = blockIdx.x * 4 + wv;

    const float* xr = x + (size_t)n * D_DIM;

    float v[4][4];
    float sum = 0.f, sumsq = 0.f;
#pragma unroll
    for (int p = 0; p < 4; ++p) {
        float4 t = *(const float4*)&xr[ln * 4 + p * 256];
        v[p][0] = t.x; v[p][1] = t.y; v[p][2] = t.z; v[p][3] = t.w;
#pragma unroll
        for (int c = 0; c < 4; ++c) { sum += v[p][c]; sumsq += v[p][c] * v[p][c]; }
    }
#pragma unroll
    for (int m = 1; m < 64; m <<= 1) {
        sum   += __shfl_xor(sum, m, 64);
        sumsq += __shfl_xor(sumsq, m, 64);
    }
    const float mu = sum * (1.0f / D_DIM);
    const float var = sumsq * (1.0f / D_DIM) - mu * mu;
    const float rstd = rsqrtf(var + 1e-5f);

    float xv[4][4];
#pragma unroll
    for (int p = 0; p < 4; ++p) {
        int col = ln * 4 + p * 256;
        float4 sc = *(const float4*)&ln_scale[col];
        float4 bi = *(const float4*)&ln_bias[col];
        const float* scp = (const float*)&sc;
        const float* bip = (const float*)&bi;
        ushort4 o;
        unsigned short* op = (unsigned short*)&o;
#pragma unroll
        for (int c = 0; c < 4; ++c) {
            float t = (v[p][c] - mu) * rstd * scp[c] + bip[c];
            xv[p][c] = t;
            op[c] = f2bf(t);
        }
        *(ushort4*)&xn[(size_t)n * D_DIM + col] = o;
    }

    float dot[E_NUM];
#pragma unroll
    for (int e = 0; e < E_NUM; ++e) {
        const float* rw = router_w + (size_t)e * D_DIM;
        float a = 0.f;
#pragma unroll
        for (int p = 0; p < 4; ++p) {
            float4 t = *(const float4*)&rw[ln * 4 + p * 256];
            const float* tp = (const float*)&t;
#pragma unroll
            for (int c = 0; c < 4; ++c) a += xv[p][c] * tp[c];
        }
        dot[e] = a;
    }
#pragma unroll
    for (int e = 0; e < E_NUM; ++e)
#pragma unroll
        for (int m = 1; m < 64; m <<= 1) dot[e] += __shfl_xor(dot[e], m, 64);

    if (ln == 0) {
        float4 g0 = make_float4(dot[0], dot[1], dot[2], dot[3]);
        float4 g1 = make_float4(dot[4], dot[5], dot[6], dot[7]);
        *(float4*)&gate_out[(size_t)n * E_NUM] = g0;
        *(float4*)&gate_out[(size_t)n * E_NUM + 4] = g1;

        int i0 = 0; float l0 = dot[0];
        for (int e = 1; e < E_NUM; ++e)
            if (dot[e] > l0) { l0 = dot[e]; i0 = e; }
        int i1 = -1; float l1 = -INFINITY;
        for (int e = 0; e < E_NUM; ++e) {
            if (e == i0) continue;
            if (dot[e] > l1) { l1 = dot[e]; i1 = e; }
        }
        float z = __expf(l1 - l0);
        float p0 = 1.0f / (1.0f + z);
        float p1 = z / (1.0f + z);
        float msk = seq_mask[n];

        tok_e[n] = (unsigned)i0 | ((unsigned)i1 << 8);
        tok_p[n] = make_float2(p0 * msk, p1 * msk);
    }
}

// ---------------------------------------------------------------------------
// Build per-expert token lists via ballot prefix-scan. grid = 8.
// ---------------------------------------------------------------------------
__global__ __launch_bounds__(256) void build_lists(
    const unsigned int* __restrict__ tok_e,
    const float2* __restrict__ tok_p,
    int* __restrict__ counts,   // [E]
    int* __restrict__ perm,     // [E, N]
    int* __restrict__ hrow,     // [E, N]
    float* __restrict__ probs)  // [E, N]
{
    const int e = blockIdx.x;
    const int tid = threadIdx.x;
    const int wv = tid >> 6, ln = tid & 63;
    __shared__ int s_base;
    __shared__ int wave_tot[4];
    if (tid == 0) s_base = 0;
    __syncthreads();

    for (int t0 = 0; t0 < N_TOK; t0 += 256) {
        int t = t0 + tid;
        unsigned pk = tok_e[t];
        int m1 = (((pk >> 8) & 0xffu) == (unsigned)e);
        int m = (((pk & 0xffu) == (unsigned)e) | m1);
        unsigned long long bal = __ballot(m);
        int pre = __popcll(bal & ((1ull << ln) - 1ull));
        if (ln == 0) wave_tot[wv] = __popcll(bal);
        __syncthreads();
        int base = s_base;
        int wbase = 0;
#pragma unroll
        for (int w = 0; w < 4; ++w) if (w < wv) wbase += wave_tot[w];
        int total = wave_tot[0] + wave_tot[1] + wave_tot[2] + wave_tot[3];
        __syncthreads();
        if (m) {
            int pos = base + wbase + pre;
            perm[e * N_TOK + pos] = t;
            hrow[e * N_TOK + pos] = t * 2 + m1;
            float2 p = tok_p[t];
            probs[e * N_TOK + pos] = m1 ? p.y : p.x;
        }
        if (tid == 0) s_base = base + total;
        __syncthreads();
    }
    if (tid == 0) counts[e] = s_base;
}

// ---------------------------------------------------------------------------
// fp32 [E][K][N] -> bf16 [E][N][K] transpose+convert. 64x64 tiles.
// ---------------------------------------------------------------------------
__global__ __launch_bounds__(256) void transpose_convert(
    const float* __restrict__ src, unsigned short* __restrict__ dst,
    int K, int N)
{
    __shared__ float ts[64][65];
    const int e = blockIdx.z;
    const int n0 = blockIdx.x * 64;
    const int k0 = blockIdx.y * 64;
    const float* S = src + (size_t)e * K * N;
    unsigned short* D = dst + (size_t)e * N * K;
    const int tid = threadIdx.x;
    const int r = tid >> 4, c4 = (tid & 15) * 4;

#pragma unroll
    for (int j = 0; j < 4; ++j) {
        float4 v = *(const float4*)&S[(size_t)(k0 + r + 16 * j) * N + n0 + c4];
        ts[r + 16 * j][c4 + 0] = v.x;
        ts[r + 16 * j][c4 + 1] = v.y;
        ts[r + 16 * j][c4 + 2] = v.z;
        ts[r + 16 * j][c4 + 3] = v.w;
    }
    __syncthreads();
#pragma unroll
    for (int j = 0; j < 4; ++j) {
        int nn = r + 16 * j;
        ushort4 o;
        o.x = f2bf(ts[c4 + 0][nn]);
        o.y = f2bf(ts[c4 + 1][nn]);
        o.z = f2bf(ts[c4 + 2][nn]);
        o.w = f2bf(ts[c4 + 3][nn]);
        *(ushort4*)&D[(size_t)(n0 + nn) * K + k0 + c4] = o;
    }
}

// ---------------------------------------------------------------------------
// Map a dense y-slot to (expert, m0) from counts. Wave-uniform scalar math.
// ---------------------------------------------------------------------------
__device__ __forceinline__ int slot_to_tile(const int* counts, int yslot, int* m0) {
    int e = -1, acc = 0, m = 0;
#pragma unroll
    for (int ee = 0; ee < E_NUM; ++ee) {
        int t = (counts[ee] + 127) >> 7;
        if (e < 0 && yslot < acc + t) { e = ee; m = (yslot - acc) << 7; }
        acc += t;
    }
    *m0 = m;
    return e;
}

// ---------------------------------------------------------------------------
// MFMA expert GEMM stage 1: h = gelu( gather(xn) @ w1t^T + b1 )
// 128x128 tile, BK=32, single-buffer, 512 thr / 8 waves, wave-tile 32x64.
// grid = (H/128, MAX_YSLOTS)
// ---------------------------------------------------------------------------
__global__ __launch_bounds__(512) void expert_gemm1(
    const unsigned short* __restrict__ xn,   // [N_TOK][D] bf16
    const unsigned short* __restrict__ wt1,  // [E][H][D] bf16 (transposed)
    const float* __restrict__ b1,            // [E][H]
    const int* __restrict__ counts,
    const int* __restrict__ perm,
    const int* __restrict__ hrow,
    unsigned short* __restrict__ hbuf)       // [N_TOK*2][H] bf16
{
    int m0;
    const int e = slot_to_tile(counts, blockIdx.y, &m0);
    if (e < 0) return;
    const int cnt = counts[e];
    const int n0 = blockIdx.x * 128;
    const int tid = threadIdx.x;
    const int wv = tid >> 6, ln = tid & 63;
    const int ml = ln & 15, q = ln >> 4;
    const int wm = (wv & 3) * 32;       // 4 waves in m
    const int wn = (wv >> 2) * 64;      // 2 waves in n

    __shared__ __align__(16) unsigned char As[128 * 64];   // 128 rows x 32 k
    __shared__ __align__(16) unsigned char Bs[128 * 64];
    __shared__ int s_tok[128];
    __shared__ int s_hr[128];

    if (tid < 128) {
        int m = m0 + tid;
        int ok = (m < cnt);
        s_tok[tid] = ok ? perm[e * N_TOK + m] : 0;
        s_hr[tid]  = ok ? hrow[e * N_TOK + m] : 0;
    }
    __syncthreads();

    const unsigned short* wte = wt1 + (size_t)e * H_DIM * D_DIM;
    // 512 threads: 1 A-chunk + 1 B-chunk each (chunk = 16 B)
    const int r_ = tid >> 2, ss = tid & 3;
    const int sg = ss ^ ((r_ >> 1) & 3);    // XOR swizzle (64B row stride)
    const unsigned short* agp = xn + (size_t)s_tok[r_] * D_DIM + sg * 8;
    const int alds = tid * 16;
    const unsigned short* bgp = wte + (size_t)(n0 + r_) * D_DIM + sg * 8;
    const int blds = tid * 16;

    f32x4 acc[2][4] = {};
    const int rslot = (q ^ ((ml >> 1) & 3)) * 16;

    for (int k0 = 0; k0 < D_DIM; k0 += 32) {
        __syncthreads();
        gload_lds16(agp + k0, As + alds);
        gload_lds16(bgp + k0, Bs + blds);
        __syncthreads();
        bf16x8 af[2], bfr[4];
#pragma unroll
        for (int i = 0; i < 2; ++i)
            af[i] = *(const bf16x8*)(As + (wm + i * 16 + ml) * 64 + rslot);
#pragma unroll
        for (int j = 0; j < 4; ++j)
            bfr[j] = *(const bf16x8*)(Bs + (wn + j * 16 + ml) * 64 + rslot);
#pragma unroll
        for (int i = 0; i < 2; ++i)
#pragma unroll
            for (int j = 0; j < 4; ++j)
                acc[i][j] = __builtin_amdgcn_mfma_f32_16x16x32_bf16(
                    af[i], bfr[j], acc[i][j], 0, 0, 0);
    }

    float bias[4];
#pragma unroll
    for (int j = 0; j < 4; ++j)
        bias[j] = b1[(size_t)e * H_DIM + n0 + wn + j * 16 + ml];

#pragma unroll
    for (int i = 0; i < 2; ++i) {
#pragma unroll
        for (int r = 0; r < 4; ++r) {
            int rl = wm + i * 16 + q * 4 + r;
            if (m0 + rl < cnt) {
                int hr = s_hr[rl];
                unsigned short* dst = hbuf + (size_t)hr * H_DIM + n0 + wn + ml;
#pragma unroll
                for (int j = 0; j < 4; ++j)
                    dst[j * 16] = f2bf(gelu_exact(acc[i][j][r] + bias[j]));
            }
        }
    }
}

// ---------------------------------------------------------------------------
// MFMA expert GEMM stage 2: ybuf[hr] = prob * gelu( h @ w2t^T + b2 )
// 128x128 tile, BK=32, single-buffer, 512 thr / 8 waves, wave-tile 32x64.
// grid = (O/128, MAX_YSLOTS)
// ---------------------------------------------------------------------------
__global__ __launch_bounds__(512) void expert_gemm2(
    const unsigned short* __restrict__ hbuf, // [N_TOK*2][H] bf16
    const unsigned short* __restrict__ wt2,  // [E][O][H] bf16 (transposed)
    const float* __restrict__ b2,            // [E][O]
    const int* __restrict__ counts,
    const int* __restrict__ perm,
    const int* __restrict__ hrow,
    const float* __restrict__ probs,
    float* __restrict__ ybuf)                // [N_TOK*2][O] fp32
{
    int m0;
    const int e = slot_to_tile(counts, blockIdx.y, &m0);
    if (e < 0) return;
    const int cnt = counts[e];
    const int n0 = blockIdx.x * 128;
    const int tid = threadIdx.x;
    const int wv = tid >> 6, ln = tid & 63;
    const int ml = ln & 15, q = ln >> 4;
    const int wm = (wv & 3) * 32;       // 4 waves in m
    const int wn = (wv >> 2) * 64;      // 2 waves in n

    __shared__ __align__(16) unsigned char As[128 * 64];
    __shared__ __align__(16) unsigned char Bs[128 * 64];
    __shared__ int s_hr[128];
    __shared__ float s_p[128];

    if (tid < 128) {
        int m = m0 + tid;
        int ok = (m < cnt);
        s_hr[tid] = ok ? hrow[e * N_TOK + m] : 0;
        s_p[tid]  = ok ? probs[e * N_TOK + m] : 0.f;
    }
    __syncthreads();

    const unsigned short* wte = wt2 + (size_t)e * O_DIM * H_DIM;
    const int r_ = tid >> 2, ss = tid & 3;
    const int sg = ss ^ ((r_ >> 1) & 3);
    const unsigned short* agp = hbuf + (size_t)s_hr[r_] * H_DIM + sg * 8;
    const int alds = tid * 16;
    const unsigned short* bgp = wte + (size_t)(n0 + r_) * H_DIM + sg * 8;
    const int blds = tid * 16;

    f32x4 acc[2][4] = {};
    const int rslot = (q ^ ((ml >> 1) & 3)) * 16;

    for (int k0 = 0; k0 < H_DIM; k0 += 32) {
        __syncthreads();
        gload_lds16(agp + k0, As + alds);
        gload_lds16(bgp + k0, Bs + blds);
        __syncthreads();
        bf16x8 af[2], bfr[4];
#pragma unroll
        for (int i = 0; i < 2; ++i)
            af[i] = *(const bf16x8*)(As + (wm + i * 16 + ml) * 64 + rslot);
#pragma unroll
        for (int j = 0; j < 4; ++j)
            bfr[j] = *(const bf16x8*)(Bs + (wn + j * 16 + ml) * 64 + rslot);
#pragma unroll
        for (int i = 0; i < 2; ++i)
#pragma unroll
            for (int j = 0; j < 4; ++j)
                acc[i][j] = __builtin_amdgcn_mfma_f32_16x16x32_bf16(
                    af[i], bfr[j], acc[i][j], 0, 0, 0);
    }

    float bias[4];
#pragma unroll
    for (int j = 0; j < 4; ++j)
        bias[j] = b2[(size_t)e * O_DIM + n0 + wn + j * 16 + ml];

#pragma unroll
    for (int i = 0; i < 2; ++i) {
#pragma unroll
        for (int r = 0; r < 4; ++r) {
            int rl = wm + i * 16 + q * 4 + r;
            if (m0 + rl < cnt) {
                int hr = s_hr[rl];
                float p = s_p[rl];
                float* dst = ybuf + (size_t)hr * O_DIM + n0 + wn + ml;
#pragma unroll
                for (int j = 0; j < 4; ++j)
                    dst[j * 16] = gelu_exact(acc[i][j][r] + bias[j]) * p;
            }
        }
    }
}

// ---------------------------------------------------------------------------
// combine: out[t] = ybuf[2t] + ybuf[2t+1]
// ---------------------------------------------------------------------------
__global__ __launch_bounds__(256) void combine_kernel(
    const float* __restrict__ ybuf, float* __restrict__ out)
{
    const size_t i = ((size_t)blockIdx.x * 256 + threadIdx.x) * 4;
    const size_t t = i / O_DIM;
    const size_t o = i % O_DIM;
    float4 a = *(const float4*)&ybuf[(t * 2) * O_DIM + o];
    float4 b = *(const float4*)&ybuf[(t * 2 + 1) * O_DIM + o];
    float4 r = make_float4(a.x + b.x, a.y + b.y, a.z + b.z, a.w + b.w);
    *(float4*)&out[i] = r;
}

// ---------------------------------------------------------------------------
extern "C" void kernel_launch(void* const* d_in, const int* in_sizes, int n_in,
                              void* d_out, int out_size, void* d_ws, size_t ws_size,
                              hipStream_t stream) {
    const float* x        = (const float*)d_in[0];
    const float* seq_mask = (const float*)d_in[1];
    const float* ln_scale = (const float*)d_in[2];
    const float* ln_bias  = (const float*)d_in[3];
    const float* router_w = (const float*)d_in[4];
    const float* w1       = (const float*)d_in[5];
    const float* b1       = (const float*)d_in[6];
    const float* w2       = (const float*)d_in[7];
    const float* b2       = (const float*)d_in[8];

    float* out      = (float*)d_out;               // [N, O]
    float* gate_out = out + (size_t)N_TOK * O_DIM; // [N, E]

    // workspace layout (~110 MB)
    char* ws = (char*)d_ws;
    unsigned short* xn = (unsigned short*)ws;              // N*D bf16   (8.4 MB)
    ws += (size_t)N_TOK * D_DIM * 2;
    unsigned short* wt = (unsigned short*)ws;              // E*H*D bf16 (33.6 MB, shared w1t/w2t)
    ws += (size_t)E_NUM * H_DIM * D_DIM * 2;
    unsigned short* hbuf = (unsigned short*)ws;            // 8192*H bf16 (33.6 MB)
    ws += (size_t)N_TOK * K_TOP * H_DIM * 2;
    float* ybuf = (float*)ws;                              // 8192*O fp32 (33.6 MB)
    ws += (size_t)N_TOK * K_TOP * O_DIM * 4;
    unsigned int* tok_e = (unsigned int*)ws; ws += (size_t)N_TOK * 4;
    float2* tok_p = (float2*)ws; ws += (size_t)N_TOK * 8;
    int* counts = (int*)ws; ws += 256;
    int* perm = (int*)ws;  ws += (size_t)E_NUM * N_TOK * 4;
    int* hrow = (int*)ws;  ws += (size_t)E_NUM * N_TOK * 4;
    float* probs = (float*)ws;

    ln_router_kernel<<<N_TOK / 4, 256, 0, stream>>>(
        x, seq_mask, ln_scale, ln_bias, router_w,
        xn, gate_out, tok_e, tok_p);

    build_lists<<<E_NUM, 256, 0, stream>>>(
        tok_e, tok_p, counts, perm, hrow, probs);

    // w1 [E][D][H] -> wt [E][H][D]
    transpose_convert<<<dim3(H_DIM / 64, D_DIM / 64, E_NUM), 256, 0, stream>>>(
        w1, wt, D_DIM, H_DIM);

    expert_gemm1<<<dim3(H_DIM / 128, MAX_YSLOTS), 512, 0, stream>>>(
        xn, wt, b1, counts, perm, hrow, hbuf);

    // w2 [E][H][O] -> wt [E][O][H]
    transpose_convert<<<dim3(O_DIM / 64, H_DIM / 64, E_NUM), 256, 0, stream>>>(
        w2, wt, H_DIM, O_DIM);

    expert_gemm2<<<dim3(O_DIM / 128, MAX_YSLOTS), 512, 0, stream>>>(
        hbuf, wt, b2, counts, perm, hrow, probs, ybuf);

    combine_kernel<<<(N_TOK * O_DIM / 4) / 256, 256, 0, stream>>>(ybuf, out);
}